// Round 2
// baseline (427.847 us; speedup 1.0000x reference)
//
#include <hip/hip_runtime.h>
#include <math.h>

#define T_SEQ 34
#define NTOK 14
#define NE (T_SEQ * NTOK) // 476
#define ROWS 32           // rows (b values) per block
#define BLK 512
#define AVS (ROWS + 1)    // Av row stride (33) -> bank (t+r)%32 patterns
#define TTS (ROWS + 1)    // toksT row stride (33) -> conflict-free

__global__ __launch_bounds__(BLK, 8) void micro_fused_kernel(
    const int* __restrict__ idx,
    const float* __restrict__ tok_emb,
    const float* __restrict__ s_amp, const float* __restrict__ s_phase,
    const float* __restrict__ s_slope, const float* __restrict__ s_offset,
    const float* __restrict__ pc_slope, const float* __restrict__ pc_int,
    const float* __restrict__ z_hi, const float* __restrict__ spec,
    const float* __restrict__ q_w, const float* __restrict__ v_w,
    const float* __restrict__ out_A, const float* __restrict__ out_B,
    const float* __restrict__ q_phase,
    const float* __restrict__ ln1_w, const float* __restrict__ ln2_w,
    const float* __restrict__ lnf_w,
    const float* __restrict__ fc1_w, const float* __restrict__ fc1_b,
    const float* __restrict__ fc2_w, const float* __restrict__ fc2_b,
    const float* __restrict__ head_w,
    float* __restrict__ out, int N)
{
    // per-(t,tok) tables
    __shared__ float4 H4[NE];      // (h2,h3,h4,h0) RMS-normed
    __shared__ float  H1f[NE];     // h1
    __shared__ float4 C3[NE];      // q_w^T @ q_rot * invsqrt(5) * log2(e)
    // attention results (a0/l, a1/l)
    __shared__ float2 Av[T_SEQ * AVS];
    // tokens, transposed [s][r] (conflict-free in both phases)
    __shared__ int    toksT[T_SEQ * TTS];
    __shared__ float PosT[T_SEQ * 3];
    __shared__ float TE[NTOK * 2];
    __shared__ float PMs[10];            // PM[j][c] = sum_i (out_A@out_B)[i][j] * v_w[i*2+c]
    __shared__ float Ws[5 * NTOK];       // head_w.T @ tok_emb.T, [d][v]
    __shared__ float ln2s[5], lnfs[5], fc1ws[10], fc1bs[2], fc2ws[10], fc2bs[5];

    const int tid = threadIdx.x;
    const int b0 = blockIdx.x * ROWS;
    const int elemBase = b0 * T_SEQ;

    // ---- stage this block's tokens (coalesced read, transposed store) ----
    for (int i = tid; i < ROWS * T_SEQ; i += BLK) {
        int g = elemBase + i;
        int v = (g < N) ? idx[g] : 0;
        int r = i / T_SEQ, s = i - r * T_SEQ;
        toksT[s * TTS + r] = v;          // bank (s+r)%32: conflict-free
    }

    // ---- build per-(t,tok) tables (NE=476 < BLK: one entry per thread) ----
    if (tid < NE) {
        const float amp = s_amp[0], ph = s_phase[0], slp = s_slope[0], off = s_offset[0];
        const float pcs = pc_slope[0], pci = pc_int[0];
        const float cph = cosf(q_phase[0]), sph = sinf(q_phase[0]);
        // 1/sqrt(HEAD_DIM) * log2(e): fold softmax scale + exp2 conversion into C3
        const float cscale = 0.44721359549995793f * 1.4426950408889634f;
        const int e = tid;
        const int t = e / NTOK, tk = e - t * NTOK;
        float px, py, pz;
        if (t == 33)      { px = 0.f;     py = 0.f;     pz = 0.f; }
        else if (t == 32) { px = z_hi[0]; py = z_hi[1]; pz = z_hi[2]; }
        else if (t == 10) { px = spec[0]; py = spec[1]; pz = spec[2]; }
        else if (t == 21) { px = spec[3]; py = spec[4]; pz = spec[5]; }
        else {
            int i = (t < 10) ? t : (t < 21 ? t - 11 : t - 22);
            float fi = (float)i;
            float ang = 0.62831853071795864769f * fi + ph;
            float mlt = 1.f + pci + pcs * fi;
            px = amp * cosf(ang) * mlt;
            py = amp * sinf(ang) * mlt;
            pz = (slp * fi + off) * mlt;
        }
        if (tk == 0) { PosT[t*3] = px; PosT[t*3+1] = py; PosT[t*3+2] = pz; }
        float x0 = tok_emb[tk * 2], x1 = tok_emb[tk * 2 + 1];
        float ssum = x0*x0 + x1*x1 + px*px + py*py + pz*pz;
        float rn = rsqrtf(ssum * 0.2f + 1e-5f);
        float h0 = x0 * rn * ln1_w[0], h1 = x1 * rn * ln1_w[1];
        float h2 = px * rn * ln1_w[2], h3 = py * rn * ln1_w[3], h4 = pz * rn * ln1_w[4];
        float q0 = q_w[0]  * h2 + q_w[1]  * h3 + q_w[2]  * h4;
        float q1 = q_w[3]  * h2 + q_w[4]  * h3 + q_w[5]  * h4;
        float q2 = q_w[6]  * h2 + q_w[7]  * h3 + q_w[8]  * h4;
        float q3 = q_w[9]  * h2 + q_w[10] * h3 + q_w[11] * h4;
        float q4 = q_w[12] * h2 + q_w[13] * h3 + q_w[14] * h4;
        float r0 = q0 * cph - q1 * sph, r1 = q0 * sph + q1 * cph;
        float r2c = q2 * cph - q3 * sph, r3 = q2 * sph + q3 * cph;
        float c0 = (r0*q_w[0] + r1*q_w[3] + r2c*q_w[6] + r3*q_w[9]  + q4*q_w[12]) * cscale;
        float c1 = (r0*q_w[1] + r1*q_w[4] + r2c*q_w[7] + r3*q_w[10] + q4*q_w[13]) * cscale;
        float c2 = (r0*q_w[2] + r1*q_w[5] + r2c*q_w[8] + r3*q_w[11] + q4*q_w[14]) * cscale;
        H4[e] = make_float4(h2, h3, h4, h0);
        H1f[e] = h1;
        C3[e] = make_float4(c0, c1, c2, 0.f);
    }
    if (tid < 28) TE[tid] = tok_emb[tid];
    if (tid < 70) { // W[d][v] = sum_c head_w[c*5+d] * tok_emb[v*2+c]
        int d = tid / NTOK, v = tid - d * NTOK;
        Ws[tid] = head_w[d] * tok_emb[v * 2] + head_w[5 + d] * tok_emb[v * 2 + 1];
    }
    if (tid < 10) { // PM[j][c]
        int j = tid >> 1, c = tid & 1;
        float acc = 0.f;
        for (int i = 0; i < 5; ++i) {
            float m5 = out_A[i*2] * out_B[j] + out_A[i*2+1] * out_B[5 + j];
            acc += m5 * v_w[i*2 + c];
        }
        PMs[tid] = acc;
    }
    if (tid < 5)  { ln2s[tid] = ln2_w[tid]; lnfs[tid] = lnf_w[tid]; fc2bs[tid] = fc2_b[tid]; }
    if (tid < 10) { fc1ws[tid] = fc1_w[tid]; fc2ws[tid] = fc2_w[tid]; }
    if (tid < 2)  { fc1bs[tid] = fc1_b[tid]; }

    __syncthreads();

    // ---- phase 1: attention, t-major, balanced pairing (t, 33-t) ----
    // Each thread: t=tg (tg+1 iters) + t=33-tg (34-tg iters) = uniform 35.
    // Wave-internal divergence <= 1 iteration.
    auto attn = [&](int t, int rr) {
        int tokt = toksT[t * TTS + rr];
        float4 c3 = C3[t * NTOK + tokt];
        float l = 0.f, a0 = 0.f, a1 = 0.f;
#pragma unroll 2
        for (int s = 0; s <= t; ++s) {
            int tok = toksT[s * TTS + rr];      // broadcast-ish, conflict-free
            int e = s * NTOK + tok;
            float4 h = H4[e];                   // <=2-way (e vs e+8), free
            float h1v = H1f[e];
            float sc = fmaf(c3.x, h.x, fmaf(c3.y, h.y, c3.z * h.z));
            float p = exp2f(sc);
            l += p;
            a0 = fmaf(p, h.w, a0);
            a1 = fmaf(p, h1v, a1);
        }
        float il = 1.f / l;
        Av[t * AVS + rr] = make_float2(a0 * il, a1 * il);
    };

    const int r = tid & 31;
    const int tg = tid >> 5;     // 0..15
    attn(tg, r);                 // t = 0..15
    attn(33 - tg, r);            // t = 33..18
    if (tid < 64)                // t = 16,17 (one wave takes the tail)
        attn(16 + (tid >> 5), tid & 31);

    __syncthreads();

    // ---- phase 2: residual + FFN + final RMS + logits, row-major (coalesced out) ----
    for (int e2 = tid; e2 < ROWS * T_SEQ; e2 += BLK) {
        int lin = elemBase + e2;
        if (lin >= N) break;
        int rr = e2 / T_SEQ;
        int t = e2 - rr * T_SEQ;
        int tok = toksT[t * TTS + rr];
        float2 a = Av[t * AVS + rr];
        float xv0 = TE[tok * 2], xv1 = TE[tok * 2 + 1];
        float xv2 = PosT[t*3], xv3 = PosT[t*3+1], xv4 = PosT[t*3+2];

        float y[5];
#pragma unroll
        for (int j = 0; j < 5; ++j)
            y[j] = (j == 0 ? xv0 : j == 1 ? xv1 : j == 2 ? xv2 : j == 3 ? xv3 : xv4)
                 + PMs[j*2] * a.x + PMs[j*2+1] * a.y;

        float s2 = y[0]*y[0] + y[1]*y[1] + y[2]*y[2] + y[3]*y[3] + y[4]*y[4];
        float r2 = rsqrtf(s2 * 0.2f + 1e-5f);
        float hh[5];
#pragma unroll
        for (int j = 0; j < 5; ++j) hh[j] = y[j] * r2 * ln2s[j];

        float u0 = fc1bs[0], u1 = fc1bs[1];
#pragma unroll
        for (int j = 0; j < 5; ++j) { u0 += hh[j] * fc1ws[j]; u1 += hh[j] * fc1ws[5 + j]; }
        float g0 = 0.5f * u0 * (1.f + erff(u0 * 0.70710678118654752f));
        float g1v = 0.5f * u1 * (1.f + erff(u1 * 0.70710678118654752f));

        float y2[5]; float s3 = 0.f;
#pragma unroll
        for (int j = 0; j < 5; ++j) {
            y2[j] = y[j] + g0 * fc2ws[j * 2] + g1v * fc2ws[j * 2 + 1] + fc2bs[j];
            s3 += y2[j] * y2[j];
        }
        float r3 = rsqrtf(s3 * 0.2f + 1e-5f);
        float z[5];
#pragma unroll
        for (int j = 0; j < 5; ++j) z[j] = y2[j] * r3 * lnfs[j];

        float res[14];
#pragma unroll
        for (int v = 0; v < 14; ++v)
            res[v] = z[0] * Ws[v] + z[1] * Ws[14 + v] + z[2] * Ws[28 + v]
                   + z[3] * Ws[42 + v] + z[4] * Ws[56 + v];

        float2* op = (float2*)(out + (size_t)lin * 14);
#pragma unroll
        for (int v = 0; v < 7; ++v) op[v] = make_float2(res[2 * v], res[2 * v + 1]);
    }
}

extern "C" void kernel_launch(void* const* d_in, const int* in_sizes, int n_in,
                              void* d_out, int out_size, void* d_ws, size_t ws_size,
                              hipStream_t stream) {
    const int N = in_sizes[0]; // B*T
    const int grid = (N + ROWS * T_SEQ - 1) / (ROWS * T_SEQ);
    micro_fused_kernel<<<grid, BLK, 0, stream>>>(
        (const int*)d_in[0],
        (const float*)d_in[1], (const float*)d_in[2], (const float*)d_in[3],
        (const float*)d_in[4], (const float*)d_in[5], (const float*)d_in[6],
        (const float*)d_in[7], (const float*)d_in[8], (const float*)d_in[9],
        (const float*)d_in[10], (const float*)d_in[11], (const float*)d_in[12],
        (const float*)d_in[13], (const float*)d_in[14], (const float*)d_in[15],
        (const float*)d_in[16], (const float*)d_in[17], (const float*)d_in[18],
        (const float*)d_in[19], (const float*)d_in[20], (const float*)d_in[21],
        (const float*)d_in[22],
        (float*)d_out, N);
}

// Round 3
// 237.070 us; speedup vs baseline: 1.8047x; 1.8047x over previous
//
#include <hip/hip_runtime.h>
#include <math.h>

#define T_SEQ 34
#define NTOK 14
#define NE (T_SEQ * NTOK) // 476
#define ROWS 30           // rows (b values) per block; 17 pairs x 30 rows = 510 threads
#define BLK 512
#define NEL (ROWS * T_SEQ) // 1020 elements per block
#define AVS (ROWS + 1)    // Av row stride (31)
#define TTS (ROWS + 1)    // toksT row stride (31): bank (r - s) % 32, conflict-free

__global__ __launch_bounds__(BLK, 4) void micro_fused_kernel(
    const int* __restrict__ idx,
    const float* __restrict__ tok_emb,
    const float* __restrict__ s_amp, const float* __restrict__ s_phase,
    const float* __restrict__ s_slope, const float* __restrict__ s_offset,
    const float* __restrict__ pc_slope, const float* __restrict__ pc_int,
    const float* __restrict__ z_hi, const float* __restrict__ spec,
    const float* __restrict__ q_w, const float* __restrict__ v_w,
    const float* __restrict__ out_A, const float* __restrict__ out_B,
    const float* __restrict__ q_phase,
    const float* __restrict__ ln1_w, const float* __restrict__ ln2_w,
    const float* __restrict__ lnf_w,
    const float* __restrict__ fc1_w, const float* __restrict__ fc1_b,
    const float* __restrict__ fc2_w, const float* __restrict__ fc2_b,
    const float* __restrict__ head_w,
    float* __restrict__ out, int N)
{
    // per-(t,tok) tables
    __shared__ float4 H4[NE];      // (h2,h3,h4,h0) RMS-normed
    __shared__ float  H1f[NE];     // h1
    __shared__ float4 C3[NE];      // q_w^T @ q_rot * invsqrt(5) * log2(e)
    // attention results (a0/l, a1/l)
    __shared__ float2 Av[T_SEQ * AVS];
    // tokens, transposed [s][r]
    __shared__ int    toksT[T_SEQ * TTS];
    alignas(16) __shared__ float PosT[T_SEQ * 3];
    alignas(16) __shared__ float TE[NTOK * 2];
    alignas(16) __shared__ float PMs[12];      // PM[j][c] (10 used)
    alignas(16) __shared__ float WsT[NTOK * 8]; // WsT[v][d] = (head_w.T @ tok_emb.T)[d][v], d<5
    alignas(16) __shared__ float ln2s[8], lnfs[8], fc1ws[12], fc2ws[12], fc2bs[8];
    __shared__ float fc1bs[2];

    const int tid = threadIdx.x;
    const int b0 = blockIdx.x * ROWS;
    const int elemBase = b0 * T_SEQ;

    // ---- stage this block's tokens (coalesced read, transposed store) ----
    for (int i = tid; i < NEL; i += BLK) {
        int g = elemBase + i;
        int v = (g < N) ? idx[g] : 0;
        int r = i / T_SEQ, s = i - r * T_SEQ;
        toksT[s * TTS + r] = v;
    }

    // ---- build per-(t,tok) tables (NE=476 < BLK: one entry per thread) ----
    if (tid < NE) {
        const float amp = s_amp[0], ph = s_phase[0], slp = s_slope[0], off = s_offset[0];
        const float pcs = pc_slope[0], pci = pc_int[0];
        const float cph = cosf(q_phase[0]), sph = sinf(q_phase[0]);
        // 1/sqrt(HEAD_DIM) * log2(e): fold softmax scale + exp2 conversion into C3
        const float cscale = 0.44721359549995793f * 1.4426950408889634f;
        const int e = tid;
        const int t = e / NTOK, tk = e - t * NTOK;
        float px, py, pz;
        if (t == 33)      { px = 0.f;     py = 0.f;     pz = 0.f; }
        else if (t == 32) { px = z_hi[0]; py = z_hi[1]; pz = z_hi[2]; }
        else if (t == 10) { px = spec[0]; py = spec[1]; pz = spec[2]; }
        else if (t == 21) { px = spec[3]; py = spec[4]; pz = spec[5]; }
        else {
            int i = (t < 10) ? t : (t < 21 ? t - 11 : t - 22);
            float fi = (float)i;
            float ang = 0.62831853071795864769f * fi + ph;
            float mlt = 1.f + pci + pcs * fi;
            px = amp * cosf(ang) * mlt;
            py = amp * sinf(ang) * mlt;
            pz = (slp * fi + off) * mlt;
        }
        if (tk == 0) { PosT[t*3] = px; PosT[t*3+1] = py; PosT[t*3+2] = pz; }
        float x0 = tok_emb[tk * 2], x1 = tok_emb[tk * 2 + 1];
        float ssum = x0*x0 + x1*x1 + px*px + py*py + pz*pz;
        float rn = rsqrtf(ssum * 0.2f + 1e-5f);
        float h0 = x0 * rn * ln1_w[0], h1 = x1 * rn * ln1_w[1];
        float h2 = px * rn * ln1_w[2], h3 = py * rn * ln1_w[3], h4 = pz * rn * ln1_w[4];
        float q0 = q_w[0]  * h2 + q_w[1]  * h3 + q_w[2]  * h4;
        float q1 = q_w[3]  * h2 + q_w[4]  * h3 + q_w[5]  * h4;
        float q2 = q_w[6]  * h2 + q_w[7]  * h3 + q_w[8]  * h4;
        float q3 = q_w[9]  * h2 + q_w[10] * h3 + q_w[11] * h4;
        float q4 = q_w[12] * h2 + q_w[13] * h3 + q_w[14] * h4;
        float r0 = q0 * cph - q1 * sph, r1 = q0 * sph + q1 * cph;
        float r2c = q2 * cph - q3 * sph, r3 = q2 * sph + q3 * cph;
        float c0 = (r0*q_w[0] + r1*q_w[3] + r2c*q_w[6] + r3*q_w[9]  + q4*q_w[12]) * cscale;
        float c1 = (r0*q_w[1] + r1*q_w[4] + r2c*q_w[7] + r3*q_w[10] + q4*q_w[13]) * cscale;
        float c2 = (r0*q_w[2] + r1*q_w[5] + r2c*q_w[8] + r3*q_w[11] + q4*q_w[14]) * cscale;
        H4[e] = make_float4(h2, h3, h4, h0);
        H1f[e] = h1;
        C3[e] = make_float4(c0, c1, c2, 0.f);
    }
    if (tid < 28) TE[tid] = tok_emb[tid];
    if (tid < 70) { // WsT[v][d] = sum_c head_w[c*5+d] * tok_emb[v*2+c]
        int v = tid / 5, d = tid - v * 5;
        WsT[v * 8 + d] = head_w[d] * tok_emb[v * 2] + head_w[5 + d] * tok_emb[v * 2 + 1];
    }
    if (tid < 10) { // PM[j][c] = sum_i (out_A@out_B)[i][j] * v_w[i*2+c]
        int j = tid >> 1, c = tid & 1;
        float acc = 0.f;
        for (int i = 0; i < 5; ++i) {
            float m5 = out_A[i*2] * out_B[j] + out_A[i*2+1] * out_B[5 + j];
            acc += m5 * v_w[i*2 + c];
        }
        PMs[tid] = acc;
    }
    if (tid < 5)  { ln2s[tid] = ln2_w[tid]; lnfs[tid] = lnf_w[tid]; fc2bs[tid] = fc2_b[tid]; }
    if (tid < 10) { fc1ws[tid] = fc1_w[tid]; fc2ws[tid] = fc2_w[tid]; }
    if (tid < 2)  { fc1bs[tid] = fc1_b[tid]; }

    __syncthreads();

    // ---- phase 1: attention. Perfectly balanced pairing: thread (p,r) does
    //      t=p (p+1 iters) and t=33-p (34-p iters) = uniform 35 per thread. ----
    auto attn = [&](int t, int rr) {
        int tokt = toksT[t * TTS + rr];
        float4 c3 = C3[t * NTOK + tokt];
        float l = 0.f, a0 = 0.f, a1 = 0.f;
#pragma unroll 2
        for (int s = 0; s <= t; ++s) {
            int tok = toksT[s * TTS + rr];
            int e = s * NTOK + tok;
            float4 h = H4[e];
            float h1v = H1f[e];
            float sc = fmaf(c3.x, h.x, fmaf(c3.y, h.y, c3.z * h.z));
            float p = exp2f(sc);
            l += p;
            a0 = fmaf(p, h.w, a0);
            a1 = fmaf(p, h1v, a1);
        }
        float il = 1.f / l;
        Av[t * AVS + rr] = make_float2(a0 * il, a1 * il);
    };

    if (tid < 17 * ROWS) {       // 510 threads active
        int p = tid / ROWS;      // 0..16
        int r = tid - p * ROWS;  // 0..29
        attn(p, r);              // t = 0..16
        attn(33 - p, r);         // t = 33..17
    }

    __syncthreads();

    // ---- phase 2: residual + FFN + final RMS + logits.
    //      Each thread handles elements tid and tid+512, sharing weight reads. ----
    float zA[5], zB[5];
    int linA = elemBase + tid;
    int linB = elemBase + tid + BLK;
    bool va = (linA < N);                       // tid < 1020 always true here
    bool vb = (tid + BLK < NEL) && (linB < N);

    auto prep = [&](int e2, float* z) {
        int rr = e2 / T_SEQ;
        int t = e2 - rr * T_SEQ;
        int tok = toksT[t * TTS + rr];
        float2 a = Av[t * AVS + rr];
        float xv0 = TE[tok * 2], xv1 = TE[tok * 2 + 1];
        float xv2 = PosT[t*3], xv3 = PosT[t*3+1], xv4 = PosT[t*3+2];

        float y[5];
#pragma unroll
        for (int j = 0; j < 5; ++j)
            y[j] = (j == 0 ? xv0 : j == 1 ? xv1 : j == 2 ? xv2 : j == 3 ? xv3 : xv4)
                 + PMs[j*2] * a.x + PMs[j*2+1] * a.y;

        float s2 = y[0]*y[0] + y[1]*y[1] + y[2]*y[2] + y[3]*y[3] + y[4]*y[4];
        float r2 = rsqrtf(s2 * 0.2f + 1e-5f);
        float hh[5];
#pragma unroll
        for (int j = 0; j < 5; ++j) hh[j] = y[j] * r2 * ln2s[j];

        float u0 = fc1bs[0], u1 = fc1bs[1];
#pragma unroll
        for (int j = 0; j < 5; ++j) { u0 += hh[j] * fc1ws[j]; u1 += hh[j] * fc1ws[5 + j]; }
        float g0 = 0.5f * u0 * (1.f + erff(u0 * 0.70710678118654752f));
        float g1v = 0.5f * u1 * (1.f + erff(u1 * 0.70710678118654752f));

        float y2[5]; float s3 = 0.f;
#pragma unroll
        for (int j = 0; j < 5; ++j) {
            y2[j] = y[j] + g0 * fc2ws[j * 2] + g1v * fc2ws[j * 2 + 1] + fc2bs[j];
            s3 += y2[j] * y2[j];
        }
        float r3 = rsqrtf(s3 * 0.2f + 1e-5f);
#pragma unroll
        for (int j = 0; j < 5; ++j) z[j] = y2[j] * r3 * lnfs[j];
    };

    if (va) prep(tid, zA);
    if (vb) prep(tid + BLK, zB);

    float2* opA = (float2*)(out + (size_t)linA * 14);
    float2* opB = (float2*)(out + (size_t)linB * 14);
#pragma unroll
    for (int v = 0; v < 7; ++v) {
        // logits 2v and 2v+1; weight reads shared by both elements
        float4 w0 = *(const float4*)&WsT[(2*v) * 8];
        float  w4 = WsT[(2*v) * 8 + 4];
        float4 u0 = *(const float4*)&WsT[(2*v+1) * 8];
        float  u4 = WsT[(2*v+1) * 8 + 4];
        if (va) {
            float rA = zA[0]*w0.x + zA[1]*w0.y + zA[2]*w0.z + zA[3]*w0.w + zA[4]*w4;
            float rB = zA[0]*u0.x + zA[1]*u0.y + zA[2]*u0.z + zA[3]*u0.w + zA[4]*u4;
            opA[v] = make_float2(rA, rB);
        }
        if (vb) {
            float rA = zB[0]*w0.x + zB[1]*w0.y + zB[2]*w0.z + zB[3]*w0.w + zB[4]*w4;
            float rB = zB[0]*u0.x + zB[1]*u0.y + zB[2]*u0.z + zB[3]*u0.w + zB[4]*u4;
            opB[v] = make_float2(rA, rB);
        }
    }
}

extern "C" void kernel_launch(void* const* d_in, const int* in_sizes, int n_in,
                              void* d_out, int out_size, void* d_ws, size_t ws_size,
                              hipStream_t stream) {
    const int N = in_sizes[0]; // B*T
    const int grid = (N + NEL - 1) / NEL;
    micro_fused_kernel<<<grid, BLK, 0, stream>>>(
        (const int*)d_in[0],
        (const float*)d_in[1], (const float*)d_in[2], (const float*)d_in[3],
        (const float*)d_in[4], (const float*)d_in[5], (const float*)d_in[6],
        (const float*)d_in[7], (const float*)d_in[8], (const float*)d_in[9],
        (const float*)d_in[10], (const float*)d_in[11], (const float*)d_in[12],
        (const float*)d_in[13], (const float*)d_in[14], (const float*)d_in[15],
        (const float*)d_in[16], (const float*)d_in[17], (const float*)d_in[18],
        (const float*)d_in[19], (const float*)d_in[20], (const float*)d_in[21],
        (const float*)d_in[22],
        (float*)d_out, N);
}